// Round 12
// baseline (339.018 us; speedup 1.0000x reference)
//
#include <hip/hip_runtime.h>
#include <math.h>

// ---------------- constants ----------------
#define NTOT   33600      // 25600 + 6400 + 1600
#define NSEL   3000       // 3 levels x top-1000
#define CAND_CAP 8192
#define NWORDS 47         // ceil(3000/64)
#define NROWS_PAD 3008    // 47*64
#define FCAP 4            // sparse cross-chunk entries per row (overflow -> dense fallback)
#define NGRP 525          // 64-pixel groups: 400 + 100 + 25
#define WPER 21760        // 256 + 1024 + 20480 weights per level
#define NSLC 10           // class slices (10 chunks x 8 classes)
#define NTRI 1128         // 47*48/2 upper-triangle word pairs
#define NPAIR 16800       // NTOT/2 pixel pairs
#define ZTOT 199612       // u32s to zero: hist(196608) + cnt(4) + cntGi(3000)

struct P21 {
  const float* feat[3];
  const float* Wobj[3];
  const float* bobj[3];
  const float* Wcls[3];
  const float* bcls[3];
  const float* Wreg[3];
  const float* breg[3];
};

// map (64-px group, lane) -> (level, pixel, global index, dims)
__device__ __forceinline__ void level_of_group(int grp, int lane, int& l, int& p, int& g,
                                               int& HW, int& Wd, double& stride) {
  if (grp < 400)      { l = 0; p = grp * 64 + lane;         g = p;         HW = 25600; Wd = 160; stride = 8.0;  }
  else if (grp < 500) { l = 1; p = (grp - 400) * 64 + lane; g = 25600 + p; HW = 6400;  Wd = 80;  stride = 16.0; }
  else                { l = 2; p = (grp - 500) * 64 + lane; g = 32000 + p; HW = 1600;  Wd = 40;  stride = 32.0; }
}

__device__ __forceinline__ double sigmoid_d(double x) { return 1.0 / (1.0 + exp(-x)); }

__device__ __forceinline__ unsigned long long shfl64(unsigned long long v, int src) {
  unsigned lo = (unsigned)__shfl((int)(unsigned)(v & 0xFFFFFFFFull), src, 64);
  unsigned hi = (unsigned)__shfl((int)(unsigned)(v >> 32), src, 64);
  return (((unsigned long long)hi) << 32) | (unsigned long long)lo;
}

// ---------------- K0: setup — zero hist/cnt/cntGi + f32->f64 weight conversion ----------------
// zbase = hist (hist, cnt, cntGi contiguous).  W64 per level: [0,256) Wobj | [256,1280) Wreg | [1280,21760) Wcls
__global__ __launch_bounds__(256) void k_setup(P21 P, unsigned* __restrict__ zbase,
                                               double* __restrict__ W64) {
  int id = blockIdx.x * 256 + threadIdx.x;
  if (id < ZTOT) zbase[id] = 0;
  if (id < 3 * WPER) {
    int l = id / WPER, r = id - l * WPER;
    const float* src;
    if (r < 256)        src = P.Wobj[l] + r;
    else if (r < 1280)  src = P.Wreg[l] + (r - 256);
    else                src = P.Wcls[l] + (r - 1280);
    W64[id] = (double)(*src);
  }
}

// ---------------- K1: 1x1 convs, 11 chunks (grid.y), 256 thr, 2 px/thread, reg prefetch ----------------
// chunk 0: obj + 4 reg.  chunk 1..10: classes [8(ch-1), +8).
// Per-pixel, per-output accumulation is one sequential c=0..255 fma chain -> bit-exact.
__global__ __launch_bounds__(256) void k_conv_chunk(P21 P, const double* __restrict__ W64,
    double* __restrict__ obj_t, double* __restrict__ reg_t,
    double* __restrict__ cmax, int* __restrict__ clab) {
  const int q = blockIdx.x * 256 + threadIdx.x;   // pair index
  if (q >= NPAIR) return;
  int l, p, g;
  if (q < 12800)      { l = 0; p = 2 * q;             g = p; }
  else if (q < 16000) { l = 1; p = 2 * (q - 12800);   g = 25600 + p; }
  else                { l = 2; p = 2 * (q - 16000);   g = 32000 + p; }
  const int HW = (l == 0) ? 25600 : (l == 1) ? 6400 : 1600;
  const int s2 = HW >> 1;                         // channel stride in float2 units
  const int ch = blockIdx.y;
  const float2* __restrict__ fp2 = (const float2*)(P.feat[l] + p);
  const double* __restrict__ Wl = W64 + l * WPER;

  float2 cur[8], nxt[8];
#pragma unroll
  for (int u = 0; u < 8; u++) cur[u] = fp2[u * s2];

  if (ch == 0) {
    const double* __restrict__ Wo = Wl;
    const double* __restrict__ Wr = Wl + 256;
    double o0 = (double)P.bobj[l][0], o1 = o0;
    double r0[4], r1[4];
#pragma unroll
    for (int j = 0; j < 4; j++) { r0[j] = (double)P.breg[l][j]; r1[j] = r0[j]; }
    for (int c = 0; c < 256; c += 8) {
      const int cn = (c + 8 < 256) ? (c + 8) : 248;   // clamped unconditional prefetch
#pragma unroll
      for (int u = 0; u < 8; u++) nxt[u] = fp2[(cn + u) * s2];
#pragma unroll
      for (int u = 0; u < 8; u++) {
        double x0 = (double)cur[u].x, x1 = (double)cur[u].y;
        double w = Wo[c + u];
        o0 = fma(w, x0, o0); o1 = fma(w, x1, o1);
#pragma unroll
        for (int j = 0; j < 4; j++) {
          double wr = Wr[j * 256 + c + u];
          r0[j] = fma(wr, x0, r0[j]); r1[j] = fma(wr, x1, r1[j]);
        }
      }
#pragma unroll
      for (int u = 0; u < 8; u++) cur[u] = nxt[u];
    }
    obj_t[g] = o0; obj_t[g + 1] = o1;
#pragma unroll
    for (int j = 0; j < 4; j++) { reg_t[4 * g + j] = r0[j]; reg_t[4 * g + 4 + j] = r1[j]; }
  } else {
    const int base = (ch - 1) * 8;
    const double* __restrict__ Wc = Wl + 1280 + base * 256;
    const float* __restrict__ bcls = P.bcls[l];
    double a0[8], a1[8];
#pragma unroll
    for (int j = 0; j < 8; j++) { a0[j] = (double)bcls[base + j]; a1[j] = a0[j]; }
    for (int c = 0; c < 256; c += 8) {
      const int cn = (c + 8 < 256) ? (c + 8) : 248;
#pragma unroll
      for (int u = 0; u < 8; u++) nxt[u] = fp2[(cn + u) * s2];
#pragma unroll
      for (int u = 0; u < 8; u++) {
        double x0 = (double)cur[u].x, x1 = (double)cur[u].y;
#pragma unroll
        for (int j = 0; j < 8; j++) {
          double w = Wc[j * 256 + c + u];
          a0[j] = fma(w, x0, a0[j]); a1[j] = fma(w, x1, a1[j]);
        }
      }
#pragma unroll
      for (int u = 0; u < 8; u++) cur[u] = nxt[u];
    }
    double m0 = a0[0], m1 = a1[0]; int l0 = base, l1 = base;
#pragma unroll
    for (int j = 1; j < 8; j++) {
      if (a0[j] > m0) { m0 = a0[j]; l0 = base + j; }
      if (a1[j] > m1) { m1 = a1[j]; l1 = base + j; }
    }
    cmax[(ch - 1) * NTOT + g] = m0; cmax[(ch - 1) * NTOT + g + 1] = m1;
    clab[(ch - 1) * NTOT + g] = l0; clab[(ch - 1) * NTOT + g + 1] = l1;
  }
}

// ---------------- K1b: combine 10 class-slices -> score/label/box + histogram ----------------
__global__ __launch_bounds__(64) void k_combine(
    const double* __restrict__ obj_t, const double* __restrict__ reg_t,
    const double* __restrict__ cmax, const int* __restrict__ clab,
    double* __restrict__ score_d, int* __restrict__ label_d,
    double* __restrict__ box_d, unsigned* __restrict__ hist) {
  int l, p, g, HW, Wd; double stride;
  level_of_group(blockIdx.x, threadIdx.x, l, p, g, HW, Wd, stride);

  double maxv = cmax[g]; int lab = clab[g];
#pragma unroll
  for (int k = 1; k < NSLC; k++) {
    double v = cmax[k * NTOT + g];
    int lb = clab[k * NTOT + g];
    if (v > maxv) { maxv = v; lab = lb; }   // strict > keeps earliest class on ties
  }
  double score = sigmoid_d(obj_t[g]) * sigmoid_d(maxv);
  int h = p / Wd, w = p - h * Wd;
  double ax = ((double)w + 0.5) * stride;
  double ay = ((double)h + 0.5) * stride;
  double e0 = exp(reg_t[4 * g + 0]) * stride;
  double e1 = exp(reg_t[4 * g + 1]) * stride;
  double e2 = exp(reg_t[4 * g + 2]) * stride;
  double e3 = exp(reg_t[4 * g + 3]) * stride;

  score_d[g] = score;
  label_d[g] = lab;
  box_d[4 * g + 0] = ax - e0;
  box_d[4 * g + 1] = ay - e1;
  box_d[4 * g + 2] = ax + e2;
  box_d[4 * g + 3] = ay + e3;

  unsigned key = __float_as_uint((float)score);   // score > 0 -> monotone key
  atomicAdd(&hist[l * 65536 + (key >> 16)], 1u);
}

// ---------------- K2a: per-level cutoff bin (fused sums + select), 3 blocks ----------------
__global__ __launch_bounds__(256) void k_scan(const unsigned* __restrict__ hist,
                                              unsigned* __restrict__ cutB) {
  int l = blockIdx.x;
  const unsigned* h = hist + l * 65536;
  __shared__ unsigned cs[256];
  __shared__ unsigned hb[256];
  __shared__ int s_chunk;
  __shared__ unsigned s_acc;
  int t = threadIdx.x;
  {
    const uint4* hp = (const uint4*)(h + t * 256);   // 64 independent 16B loads/thread
    unsigned s = 0;
    for (int b = 0; b < 64; b++) { uint4 v = hp[b]; s += v.x + v.y + v.z + v.w; }
    cs[t] = s;
  }
  __syncthreads();
  if (t == 0) {
    unsigned acc = 0; int chunk = 0;
    for (int tt = 255; tt >= 0; tt--) {
      if (acc + cs[tt] >= 1000u) { chunk = tt; break; }
      acc += cs[tt];
    }
    s_chunk = chunk; s_acc = acc;
  }
  __syncthreads();
  int chunk = s_chunk;
  hb[t] = h[chunk * 256 + t];
  __syncthreads();
  if (t == 0) {
    unsigned acc = s_acc;
    unsigned B = (unsigned)(chunk * 256);
    for (int b = 255; b >= 0; b--) {
      unsigned c = hb[b];
      if (acc + c >= 1000u) { B = (unsigned)(chunk * 256 + b); break; }
      acc += c;
    }
    cutB[l] = B;
  }
}

// ---------------- K2b: compact candidates with key-bin >= cutoff ----------------
__global__ __launch_bounds__(64) void k_compact(const double* __restrict__ score_d,
    const unsigned* __restrict__ cutB, unsigned* __restrict__ cnt,
    double* __restrict__ cand_s, int* __restrict__ cand_g) {
  int l, p, g, HW, Wd; double stride;
  level_of_group(blockIdx.x, threadIdx.x, l, p, g, HW, Wd, stride);
  double sc = score_d[g];
  unsigned key = __float_as_uint((float)sc);
  if ((key >> 16) >= cutB[l]) {
    unsigned pos = atomicAdd(&cnt[l], 1u);
    if (pos < CAND_CAP) {
      cand_s[l * CAND_CAP + pos] = sc;
      cand_g[l * CAND_CAP + pos] = g;
    }
  }
}

// ---------------- K2c: rank via one WAVE per candidate (parallel over compares) ----------------
__global__ __launch_bounds__(256) void k_rank(const double* __restrict__ cand_s,
    const int* __restrict__ cand_g, const unsigned* __restrict__ cnt,
    const int* __restrict__ label_d, const double* __restrict__ box_d,
    double* __restrict__ sel_s, int* __restrict__ sel_lab, double* __restrict__ sel_box) {
  const int l = blockIdx.y;
  const int M = (int)min(cnt[l], (unsigned)CAND_CAP);
  if (blockIdx.x * 4 >= M) return;                 // uniform block exit
  const int q = blockIdx.x * 4 + (threadIdx.x >> 6);   // wave's candidate
  const int lane = threadIdx.x & 63;
  const bool active = (q < M);                     // wave-uniform

  double s = 0.0; int g = 0;
  if (active) { s = cand_s[l * CAND_CAP + q]; g = cand_g[l * CAND_CAP + q]; }

  int r = 0;
  if (active) {
    for (int j = lane; j < M; j += 64) {           // coalesced 64x8B per iter
      double sj = cand_s[l * CAND_CAP + j];
      int gj = cand_g[l * CAND_CAP + j];
      r += (sj > s) || (sj == s && gj < g);        // desc by score, ties -> lower index
    }
  }
#pragma unroll
  for (int off = 32; off > 0; off >>= 1) r += __shfl_down(r, off, 64);

  if (active && lane == 0 && r < 1000) {
    int o = l * 1000 + r;
    sel_s[o] = s;
    sel_lab[o] = label_d[g];
    sel_box[4 * o + 0] = box_d[4 * g + 0];
    sel_box[4 * o + 1] = box_d[4 * g + 1];
    sel_box[4 * o + 2] = box_d[4 * g + 2];
    sel_box[4 * o + 3] = box_d[4 * g + 3];
  }
}

// ---------------- K3: stable argsort(-scores) + build sorted boxes (fused) ----------------
__global__ __launch_bounds__(256) void k_order(const double* __restrict__ sel_s,
    const int* __restrict__ sel_lab, const double* __restrict__ sel_box,
    int* __restrict__ sortIdx, double* __restrict__ sbox, int* __restrict__ svalid) {
  const int i = blockIdx.x;
  const int t = threadIdx.x;
  const double s = sel_s[i];                       // uniform -> scalar load
  int r = 0;
  for (int j = t; j < NSEL; j += 256) {            // 12 coalesced iters/thread
    double sj = sel_s[j];
    r += (sj > s) || (sj == s && j < i);
  }
#pragma unroll
  for (int off = 32; off > 0; off >>= 1) r += __shfl_down(r, off, 64);
  __shared__ int wsum[4];
  if ((t & 63) == 0) wsum[t >> 6] = r;
  __syncthreads();
  if (t == 0) {
    int rr = wsum[0] + wsum[1] + wsum[2] + wsum[3];
    sortIdx[rr] = i;
    double off = (double)sel_lab[i] * 8192.0;
    sbox[4 * rr + 0] = sel_box[4 * i + 0] + off;
    sbox[4 * rr + 1] = sel_box[4 * i + 1] + off;
    sbox[4 * rr + 2] = sel_box[4 * i + 2] + off;
    sbox[4 * rr + 3] = sel_box[4 * i + 3] + off;
    svalid[rr] = (s >= 0.05) ? 1 : 0;
  }
}

// ---------------- K4: IoU mask, upper-triangle 64x64 tiles (1D grid, triangular decode) ----------------
// Below-diagonal denseG words are never written NOR consumed (scan only re-reads
// rem lanes >= current word; fallback garbage lands only in already-consumed lanes).
__global__ __launch_bounds__(256) void k_mask(const double* __restrict__ sbox,
    unsigned long long* __restrict__ denseG, unsigned long long* __restrict__ diagG,
    unsigned short* __restrict__ entG, int* __restrict__ cntGi) {
  int k = blockIdx.x, rc = 0;
  while (k >= NWORDS - rc) { k -= NWORDS - rc; rc++; }
  const int w = rc + k;            // col word >= row word rc
  const int t = threadIdx.x, lane = t & 63, wk = t >> 6;
  const int rbase = rc * 64;
  __shared__ double rbox[256];     // 64 rows x 4 coords
  {
    int idx = rbase * 4 + t;
    rbox[t] = (idx < NSEL * 4) ? sbox[idx] : 0.0;
  }
  const int j = w * 64 + lane;
  const bool jok = (j < NSEL);
  double bx1 = 0, by1 = 0, bx2 = 0, by2 = 0, arj = 0;
  if (jok) {
    bx1 = sbox[4 * j + 0]; by1 = sbox[4 * j + 1];
    bx2 = sbox[4 * j + 2]; by2 = sbox[4 * j + 3];
    arj = (bx2 - bx1) * (by2 - by1);
  }
  __syncthreads();
#pragma unroll
  for (int rr = 0; rr < 16; rr++) {
    const int ro = wk * 16 + rr;
    const int i = rbase + ro;
    if (i >= NSEL) break;          // wave-uniform
    double x1 = rbox[ro * 4 + 0], y1 = rbox[ro * 4 + 1];
    double x2 = rbox[ro * 4 + 2], y2 = rbox[ro * 4 + 3];
    double ar = (x2 - x1) * (y2 - y1);
    bool c = false;
    if (jok && j > i) {
      double xx1 = fmax(x1, bx1), yy1 = fmax(y1, by1);
      double xx2 = fmin(x2, bx2), yy2 = fmin(y2, by2);
      double ww = fmax(1e-10, xx2 - xx1);
      double hh = fmax(1e-10, yy2 - yy1);
      double inter = ww * hh;
      double iou = inter / (ar + arj - inter + 1e-14);
      c = iou > 0.6;
    }
    unsigned long long word = __ballot(c);
    if (lane == 0) {
      denseG[(size_t)i * 48 + w] = word;
      if (w == rc) diagG[i] = word;
      else if (word) {
        unsigned long long tt = word;
        while (tt) {
          int b = __builtin_ctzll(tt); tt &= tt - 1;
          int slot = atomicAdd(&cntGi[i], 1);
          if (slot < FCAP) entG[i * FCAP + slot] = (unsigned short)(w * 64 + b);
        }
      }
    }
  }
}

// ---------------- K5: sparse serial greedy scan + final outputs (fused) ----------------
__global__ __launch_bounds__(256) void k_final(
    const unsigned long long* __restrict__ denseG, const unsigned long long* __restrict__ diagG,
    const unsigned short* __restrict__ entG, const int* __restrict__ cntGi,
    const int* __restrict__ svalid, const int* __restrict__ sortIdx,
    const double* __restrict__ sel_s, const int* __restrict__ sel_lab,
    const double* __restrict__ sel_box, float* __restrict__ out) {
  __shared__ unsigned long long diagL[NROWS_PAD];
  __shared__ unsigned short entL[NROWS_PAD * FCAP];
  __shared__ unsigned short cntL[NROWS_PAD];
  __shared__ unsigned long long validL[48];
  __shared__ unsigned long long hasWL[48];
  __shared__ unsigned long long keepWL[48];
  __shared__ unsigned char keepO[NROWS_PAD];
  const int t = threadIdx.x;
  const int lane = t & 63;

  for (int k = t; k < NSEL; k += 256) diagL[k] = diagG[k];
  for (int k = NSEL + t; k < NROWS_PAD; k += 256) diagL[k] = 0ull;
  uint2* e2 = (uint2*)entL; const uint2* eg2 = (const uint2*)entG;   // 8B = one row's FCAP
  for (int k = t; k < NSEL; k += 256) e2[k] = eg2[k];
  for (int k = NSEL + t; k < NROWS_PAD; k += 256) { uint2 z; z.x = 0; z.y = 0; e2[k] = z; }
  for (int k = t; k < NSEL; k += 256) cntL[k] = (unsigned short)cntGi[k];
  for (int k = NSEL + t; k < NROWS_PAD; k += 256) cntL[k] = 0;
  for (int i0 = t; i0 < NROWS_PAD; i0 += 256) {
    bool f = (i0 < NSEL) && (svalid[i0] != 0);
    unsigned long long b = __ballot(f);
    if ((t & 63) == 0) validL[i0 >> 6] = b;
  }
  __syncthreads();

  if (t < 64) {                    // wave 0: serial greedy scan
    for (int w = 0; w < NWORDS; w++) {
      int i = w * 64 + lane;
      bool f = (diagL[i] != 0ull) || (cntL[i] != 0);
      unsigned long long b = __ballot(f);
      if (lane == 0) hasWL[w] = b;
    }
    unsigned long long rem = 0ull;    // lane j: removed bits in word j (cross-chunk)
    unsigned long long keep = 0ull;   // lane j: final keep word j
    for (int w = 0; w < NWORDS; w++) {
      unsigned long long vw = validL[w];
      unsigned long long remw = shfl64(rem, w);
      unsigned long long win = vw & ~remw;
      unsigned long long work = hasWL[w];
      while (work) {
        int d = __builtin_ctzll(work); work &= work - 1;
        if ((win >> d) & 1ull) {
          int i = w * 64 + d;
          win &= ~diagL[i];                       // intra-chunk suppression (bits > d only)
          int c = cntL[i];
          if (c > FCAP) {
            unsigned long long rowj = (lane < NWORDS) ? denseG[(size_t)i * 48 + lane] : 0ull;
            rem |= rowj;                          // garbage lanes < w already consumed
          } else {
            for (int k = 0; k < c; k++) {
              int j = entL[i * FCAP + k];
              if ((j >> 6) == lane) rem |= 1ull << (j & 63);
            }
          }
        }
      }
      if (lane == w) keep = win;
    }
    if (lane < NWORDS) keepWL[lane] = keep;
  }
  __syncthreads();

  // scatter keep bits to original indices, then write outputs
  for (int r = t; r < NSEL; r += 256)
    keepO[sortIdx[r]] = (unsigned char)((keepWL[r >> 6] >> (r & 63)) & 1ull);
  __syncthreads();
  for (int i = t; i < NSEL; i += 256) {
#pragma unroll
    for (int c = 0; c < 4; c++) {
      double v = sel_box[4 * i + c] / 1280.0;
      v = fmin(fmax(v, 0.0), 1.0);
      out[4 * i + c] = (float)v;
    }
    out[12000 + i] = (float)sel_s[i];
    out[15000 + i] = (float)sel_lab[i];
    out[18000 + i] = keepO[i] ? 1.0f : 0.0f;
  }
}

// ---------------- launch ----------------
extern "C" void kernel_launch(void* const* d_in, const int* in_sizes, int n_in,
                              void* d_out, int out_size, void* d_ws, size_t ws_size,
                              hipStream_t stream) {
  P21 P;
  for (int l = 0; l < 3; l++) {
    P.feat[l] = (const float*)d_in[7 * l + 0];
    P.Wobj[l] = (const float*)d_in[7 * l + 1];
    P.bobj[l] = (const float*)d_in[7 * l + 2];
    P.Wcls[l] = (const float*)d_in[7 * l + 3];
    P.bcls[l] = (const float*)d_in[7 * l + 4];
    P.Wreg[l] = (const float*)d_in[7 * l + 5];
    P.breg[l] = (const float*)d_in[7 * l + 6];
  }

  char* ws = (char*)d_ws;
  size_t off = 0;
  auto alloc = [&](size_t bytes) -> char* {
    char* p = ws + off;
    off += (bytes + 15) & ~(size_t)15;
    return p;
  };
  double* score_d  = (double*)alloc((size_t)NTOT * 8);
  double* box_d    = (double*)alloc((size_t)NTOT * 4 * 8);
  int*    label_d  = (int*)   alloc((size_t)NTOT * 4);
  double* obj_t    = (double*)alloc((size_t)NTOT * 8);
  double* reg_t    = (double*)alloc((size_t)NTOT * 4 * 8);
  double* cmax     = (double*)alloc((size_t)NSLC * NTOT * 8);
  int*    clab     = (int*)   alloc((size_t)NSLC * NTOT * 4);
  double* W64      = (double*)alloc((size_t)3 * WPER * 8);
  double* sel_s    = (double*)alloc((size_t)NSEL * 8);
  double* sel_box  = (double*)alloc((size_t)NSEL * 4 * 8);
  int*    sel_lab  = (int*)   alloc((size_t)NSEL * 4);
  int*    sortIdx  = (int*)   alloc((size_t)NSEL * 4);
  double* sbox     = (double*)alloc((size_t)NSEL * 4 * 8);
  int*    svalid   = (int*)   alloc((size_t)NSEL * 4);
  double* cand_s   = (double*)alloc((size_t)3 * CAND_CAP * 8);
  int*    cand_g   = (int*)   alloc((size_t)3 * CAND_CAP * 4);
  unsigned long long* denseG = (unsigned long long*)alloc((size_t)NSEL * 48 * 8);
  unsigned long long* diagG  = (unsigned long long*)alloc((size_t)NSEL * 8);
  unsigned short*     entG   = (unsigned short*)alloc((size_t)NSEL * FCAP * 2);
  unsigned* hist   = (unsigned*)alloc((size_t)3 * 65536 * 4);   // zero block: hist+cnt+cntGi
  unsigned* cnt    = (unsigned*)alloc(16);
  int*      cntGi  = (int*)   alloc((size_t)NSEL * 4);
  unsigned* cutB   = (unsigned*)alloc(16);

  k_setup   <<<(ZTOT + 255) / 256, 256, 0, stream>>>(P, hist, W64);
  dim3 cgrid(66, 11, 1);
  k_conv_chunk<<<cgrid, 256, 0, stream>>>(P, W64, obj_t, reg_t, cmax, clab);
  k_combine <<<NGRP, 64, 0, stream>>>(obj_t, reg_t, cmax, clab, score_d, label_d, box_d, hist);
  k_scan    <<<3, 256, 0, stream>>>(hist, cutB);
  k_compact <<<NGRP, 64, 0, stream>>>(score_d, cutB, cnt, cand_s, cand_g);
  dim3 rgrid(CAND_CAP / 4, 3, 1);
  k_rank    <<<rgrid, 256, 0, stream>>>(cand_s, cand_g, cnt, label_d, box_d,
                                        sel_s, sel_lab, sel_box);
  k_order   <<<NSEL, 256, 0, stream>>>(sel_s, sel_lab, sel_box, sortIdx, sbox, svalid);
  k_mask    <<<NTRI, 256, 0, stream>>>(sbox, denseG, diagG, entG, cntGi);
  k_final   <<<1, 256, 0, stream>>>(denseG, diagG, entG, cntGi, svalid, sortIdx,
                                    sel_s, sel_lab, sel_box, (float*)d_out);
}

// Round 13
// 266.053 us; speedup vs baseline: 1.2743x; 1.2743x over previous
//
#include <hip/hip_runtime.h>
#include <math.h>

// ---------------- constants ----------------
#define NTOT   33600      // 25600 + 6400 + 1600
#define NSEL   3000       // 3 levels x top-1000
#define CAND_CAP 8192
#define NWORDS 47         // ceil(3000/64)
#define NROWS_PAD 3008    // 47*64
#define FCAP 4            // sparse cross-chunk entries per row (overflow -> dense fallback)
#define NGRP 525          // 64-pixel groups: 400 + 100 + 25
#define WPER 21760        // 256 + 1024 + 20480 weights per level
#define NSLC 10           // class slices (10 chunks x 8 classes)
#define NTRI 1128         // 47*48/2 upper-triangle word pairs
#define ZTOT 199612       // u32s to zero: hist(196608) + cnt(4) + cntGi(3000)

struct P21 {
  const float* feat[3];
  const float* Wobj[3];
  const float* bobj[3];
  const float* Wcls[3];
  const float* bcls[3];
  const float* Wreg[3];
  const float* breg[3];
};

// map (block, thread) -> (level, pixel-in-level, global index)  [132-block, 256-thread form]
__device__ __forceinline__ void level_of_block(int b, int t, int& l, int& p, int& g, int& HW) {
  if (b < 100)      { l = 0; p = b * 256 + t;         g = p;          HW = 25600; }
  else if (b < 125) { l = 1; p = (b - 100) * 256 + t; g = 25600 + p;  HW = 6400;  }
  else              { l = 2; p = (b - 125) * 256 + t; g = 32000 + p;  HW = 1600;  }
}

// map (64-px group, lane) -> (level, pixel, global index, dims)
__device__ __forceinline__ void level_of_group(int grp, int lane, int& l, int& p, int& g,
                                               int& HW, int& Wd, double& stride) {
  if (grp < 400)      { l = 0; p = grp * 64 + lane;         g = p;         HW = 25600; Wd = 160; stride = 8.0;  }
  else if (grp < 500) { l = 1; p = (grp - 400) * 64 + lane; g = 25600 + p; HW = 6400;  Wd = 80;  stride = 16.0; }
  else                { l = 2; p = (grp - 500) * 64 + lane; g = 32000 + p; HW = 1600;  Wd = 40;  stride = 32.0; }
}

__device__ __forceinline__ double sigmoid_d(double x) { return 1.0 / (1.0 + exp(-x)); }

__device__ __forceinline__ unsigned long long shfl64(unsigned long long v, int src) {
  unsigned lo = (unsigned)__shfl((int)(unsigned)(v & 0xFFFFFFFFull), src, 64);
  unsigned hi = (unsigned)__shfl((int)(unsigned)(v >> 32), src, 64);
  return (((unsigned long long)hi) << 32) | (unsigned long long)lo;
}

// ---------------- K0: setup — zero hist/cnt/cntGi + f32->f64 weight conversion ----------------
// zbase = hist (hist, cnt, cntGi contiguous).  W64 per level: [0,256) Wobj | [256,1280) Wreg | [1280,21760) Wcls
__global__ __launch_bounds__(256) void k_setup(P21 P, unsigned* __restrict__ zbase,
                                               double* __restrict__ W64) {
  int id = blockIdx.x * 256 + threadIdx.x;
  if (id < ZTOT) zbase[id] = 0;
  if (id < 3 * WPER) {
    int l = id / WPER, r = id - l * WPER;
    const float* src;
    if (r < 256)        src = P.Wobj[l] + r;
    else if (r < 1280)  src = P.Wreg[l] + (r - 256);
    else                src = P.Wcls[l] + (r - 1280);
    W64[id] = (double)(*src);
  }
}

// ---------------- K1: 1x1 convs, 11 chunks (grid.y), 256 thr, 1 px/thread, unroll 16 ----------------
// chunk 0: obj + 4 reg.  chunk 1..10: classes [8(ch-1), +8).
// Per-output accumulation is one sequential c=0..255 fma chain (unroll keeps
// each chain in order) -> values identical to prior rounds (absmax 0.0).
__global__ __launch_bounds__(256) void k_conv_chunk(P21 P, const double* __restrict__ W64,
    double* __restrict__ obj_t, double* __restrict__ reg_t,
    double* __restrict__ cmax, int* __restrict__ clab) {
  int l, p, g, HW;
  level_of_block(blockIdx.x, threadIdx.x, l, p, g, HW);
  if (p >= HW) return;
  const int ch = blockIdx.y;
  const float* __restrict__ fp = P.feat[l] + p;
  const double* __restrict__ Wl = W64 + l * WPER;

  if (ch == 0) {
    const double* __restrict__ Wo = Wl;            // 256
    const double* __restrict__ Wr = Wl + 256;      // 4 x 256
    double accO = (double)P.bobj[l][0];
    double accR[4];
#pragma unroll
    for (int j = 0; j < 4; j++) accR[j] = (double)P.breg[l][j];
    for (int c = 0; c < 256; c += 16) {
      double xc[16];
#pragma unroll
      for (int u = 0; u < 16; u++) xc[u] = (double)fp[(c + u) * HW];
#pragma unroll
      for (int u = 0; u < 16; u++) {
        accO = fma(Wo[c + u], xc[u], accO);
#pragma unroll
        for (int j = 0; j < 4; j++)
          accR[j] = fma(Wr[j * 256 + c + u], xc[u], accR[j]);
      }
    }
    obj_t[g] = accO;
#pragma unroll
    for (int j = 0; j < 4; j++) reg_t[4 * g + j] = accR[j];
  } else {
    const int base = (ch - 1) * 8;
    const double* __restrict__ Wc = Wl + 1280 + base * 256;   // 8 x 256
    const float* __restrict__ bcls = P.bcls[l];
    double a[8];
#pragma unroll
    for (int j = 0; j < 8; j++) a[j] = (double)bcls[base + j];
    for (int c = 0; c < 256; c += 16) {
      double xc[16];
#pragma unroll
      for (int u = 0; u < 16; u++) xc[u] = (double)fp[(c + u) * HW];
#pragma unroll
      for (int u = 0; u < 16; u++) {
#pragma unroll
        for (int j = 0; j < 8; j++)
          a[j] = fma(Wc[j * 256 + c + u], xc[u], a[j]);
      }
    }
    double maxv = a[0]; int lab = base;
#pragma unroll
    for (int j = 1; j < 8; j++) if (a[j] > maxv) { maxv = a[j]; lab = base + j; }
    cmax[(ch - 1) * NTOT + g] = maxv;
    clab[(ch - 1) * NTOT + g] = lab;
  }
}

// ---------------- K1b: combine 10 class-slices -> score/label/box + histogram ----------------
__global__ __launch_bounds__(64) void k_combine(
    const double* __restrict__ obj_t, const double* __restrict__ reg_t,
    const double* __restrict__ cmax, const int* __restrict__ clab,
    double* __restrict__ score_d, int* __restrict__ label_d,
    double* __restrict__ box_d, unsigned* __restrict__ hist) {
  int l, p, g, HW, Wd; double stride;
  level_of_group(blockIdx.x, threadIdx.x, l, p, g, HW, Wd, stride);

  double maxv = cmax[g]; int lab = clab[g];
#pragma unroll
  for (int k = 1; k < NSLC; k++) {
    double v = cmax[k * NTOT + g];
    int lb = clab[k * NTOT + g];
    if (v > maxv) { maxv = v; lab = lb; }   // strict > keeps earliest class on ties
  }
  double score = sigmoid_d(obj_t[g]) * sigmoid_d(maxv);
  int h = p / Wd, w = p - h * Wd;
  double ax = ((double)w + 0.5) * stride;
  double ay = ((double)h + 0.5) * stride;
  double e0 = exp(reg_t[4 * g + 0]) * stride;
  double e1 = exp(reg_t[4 * g + 1]) * stride;
  double e2 = exp(reg_t[4 * g + 2]) * stride;
  double e3 = exp(reg_t[4 * g + 3]) * stride;

  score_d[g] = score;
  label_d[g] = lab;
  box_d[4 * g + 0] = ax - e0;
  box_d[4 * g + 1] = ay - e1;
  box_d[4 * g + 2] = ax + e2;
  box_d[4 * g + 3] = ay + e3;

  unsigned key = __float_as_uint((float)score);   // score > 0 -> monotone key
  atomicAdd(&hist[l * 65536 + (key >> 16)], 1u);
}

// ---------------- K2a: per-level cutoff bin (fused sums + select), 3 blocks ----------------
__global__ __launch_bounds__(256) void k_scan(const unsigned* __restrict__ hist,
                                              unsigned* __restrict__ cutB) {
  int l = blockIdx.x;
  const unsigned* h = hist + l * 65536;
  __shared__ unsigned cs[256];
  __shared__ unsigned hb[256];
  __shared__ int s_chunk;
  __shared__ unsigned s_acc;
  int t = threadIdx.x;
  {
    const uint4* hp = (const uint4*)(h + t * 256);   // 64 independent 16B loads/thread
    unsigned s = 0;
    for (int b = 0; b < 64; b++) { uint4 v = hp[b]; s += v.x + v.y + v.z + v.w; }
    cs[t] = s;
  }
  __syncthreads();
  if (t == 0) {
    unsigned acc = 0; int chunk = 0;
    for (int tt = 255; tt >= 0; tt--) {
      if (acc + cs[tt] >= 1000u) { chunk = tt; break; }
      acc += cs[tt];
    }
    s_chunk = chunk; s_acc = acc;
  }
  __syncthreads();
  int chunk = s_chunk;
  hb[t] = h[chunk * 256 + t];
  __syncthreads();
  if (t == 0) {
    unsigned acc = s_acc;
    unsigned B = (unsigned)(chunk * 256);
    for (int b = 255; b >= 0; b--) {
      unsigned c = hb[b];
      if (acc + c >= 1000u) { B = (unsigned)(chunk * 256 + b); break; }
      acc += c;
    }
    cutB[l] = B;
  }
}

// ---------------- K2b: compact candidates with key-bin >= cutoff ----------------
__global__ __launch_bounds__(64) void k_compact(const double* __restrict__ score_d,
    const unsigned* __restrict__ cutB, unsigned* __restrict__ cnt,
    double* __restrict__ cand_s, int* __restrict__ cand_g) {
  int l, p, g, HW, Wd; double stride;
  level_of_group(blockIdx.x, threadIdx.x, l, p, g, HW, Wd, stride);
  double sc = score_d[g];
  unsigned key = __float_as_uint((float)sc);
  if ((key >> 16) >= cutB[l]) {
    unsigned pos = atomicAdd(&cnt[l], 1u);
    if (pos < CAND_CAP) {
      cand_s[l * CAND_CAP + pos] = sc;
      cand_g[l * CAND_CAP + pos] = g;
    }
  }
}

// ---------------- K2c: rank via one WAVE per candidate (parallel over compares) ----------------
__global__ __launch_bounds__(256) void k_rank(const double* __restrict__ cand_s,
    const int* __restrict__ cand_g, const unsigned* __restrict__ cnt,
    const int* __restrict__ label_d, const double* __restrict__ box_d,
    double* __restrict__ sel_s, int* __restrict__ sel_lab, double* __restrict__ sel_box) {
  const int l = blockIdx.y;
  const int M = (int)min(cnt[l], (unsigned)CAND_CAP);
  if (blockIdx.x * 4 >= M) return;                 // uniform block exit
  const int q = blockIdx.x * 4 + (threadIdx.x >> 6);   // wave's candidate
  const int lane = threadIdx.x & 63;
  const bool active = (q < M);                     // wave-uniform

  double s = 0.0; int g = 0;
  if (active) { s = cand_s[l * CAND_CAP + q]; g = cand_g[l * CAND_CAP + q]; }

  int r = 0;
  if (active) {
    for (int j = lane; j < M; j += 64) {           // coalesced 64x8B per iter
      double sj = cand_s[l * CAND_CAP + j];
      int gj = cand_g[l * CAND_CAP + j];
      r += (sj > s) || (sj == s && gj < g);        // desc by score, ties -> lower index
    }
  }
#pragma unroll
  for (int off = 32; off > 0; off >>= 1) r += __shfl_down(r, off, 64);

  if (active && lane == 0 && r < 1000) {
    int o = l * 1000 + r;
    sel_s[o] = s;
    sel_lab[o] = label_d[g];
    sel_box[4 * o + 0] = box_d[4 * g + 0];
    sel_box[4 * o + 1] = box_d[4 * g + 1];
    sel_box[4 * o + 2] = box_d[4 * g + 2];
    sel_box[4 * o + 3] = box_d[4 * g + 3];
  }
}

// ---------------- K3: stable argsort(-scores) + build sorted boxes (fused) ----------------
__global__ __launch_bounds__(256) void k_order(const double* __restrict__ sel_s,
    const int* __restrict__ sel_lab, const double* __restrict__ sel_box,
    int* __restrict__ sortIdx, double* __restrict__ sbox, int* __restrict__ svalid) {
  const int i = blockIdx.x;
  const int t = threadIdx.x;
  const double s = sel_s[i];                       // uniform -> scalar load
  int r = 0;
  for (int j = t; j < NSEL; j += 256) {            // 12 coalesced iters/thread
    double sj = sel_s[j];
    r += (sj > s) || (sj == s && j < i);
  }
#pragma unroll
  for (int off = 32; off > 0; off >>= 1) r += __shfl_down(r, off, 64);
  __shared__ int wsum[4];
  if ((t & 63) == 0) wsum[t >> 6] = r;
  __syncthreads();
  if (t == 0) {
    int rr = wsum[0] + wsum[1] + wsum[2] + wsum[3];
    sortIdx[rr] = i;
    double off = (double)sel_lab[i] * 8192.0;
    sbox[4 * rr + 0] = sel_box[4 * i + 0] + off;
    sbox[4 * rr + 1] = sel_box[4 * i + 1] + off;
    sbox[4 * rr + 2] = sel_box[4 * i + 2] + off;
    sbox[4 * rr + 3] = sel_box[4 * i + 3] + off;
    svalid[rr] = (s >= 0.05) ? 1 : 0;
  }
}

// ---------------- K4: IoU mask, upper-triangle 64x64 tiles (1D grid, triangular decode) ----------------
// Below-diagonal denseG words are never written NOR consumed (scan only re-reads
// rem lanes >= current word; fallback garbage lands only in already-consumed lanes).
__global__ __launch_bounds__(256) void k_mask(const double* __restrict__ sbox,
    unsigned long long* __restrict__ denseG, unsigned long long* __restrict__ diagG,
    unsigned short* __restrict__ entG, int* __restrict__ cntGi) {
  int k = blockIdx.x, rc = 0;
  while (k >= NWORDS - rc) { k -= NWORDS - rc; rc++; }
  const int w = rc + k;            // col word >= row word rc
  const int t = threadIdx.x, lane = t & 63, wk = t >> 6;
  const int rbase = rc * 64;
  __shared__ double rbox[256];     // 64 rows x 4 coords
  {
    int idx = rbase * 4 + t;
    rbox[t] = (idx < NSEL * 4) ? sbox[idx] : 0.0;
  }
  const int j = w * 64 + lane;
  const bool jok = (j < NSEL);
  double bx1 = 0, by1 = 0, bx2 = 0, by2 = 0, arj = 0;
  if (jok) {
    bx1 = sbox[4 * j + 0]; by1 = sbox[4 * j + 1];
    bx2 = sbox[4 * j + 2]; by2 = sbox[4 * j + 3];
    arj = (bx2 - bx1) * (by2 - by1);
  }
  __syncthreads();
#pragma unroll
  for (int rr = 0; rr < 16; rr++) {
    const int ro = wk * 16 + rr;
    const int i = rbase + ro;
    if (i >= NSEL) break;          // wave-uniform
    double x1 = rbox[ro * 4 + 0], y1 = rbox[ro * 4 + 1];
    double x2 = rbox[ro * 4 + 2], y2 = rbox[ro * 4 + 3];
    double ar = (x2 - x1) * (y2 - y1);
    bool c = false;
    if (jok && j > i) {
      double xx1 = fmax(x1, bx1), yy1 = fmax(y1, by1);
      double xx2 = fmin(x2, bx2), yy2 = fmin(y2, by2);
      double ww = fmax(1e-10, xx2 - xx1);
      double hh = fmax(1e-10, yy2 - yy1);
      double inter = ww * hh;
      double iou = inter / (ar + arj - inter + 1e-14);
      c = iou > 0.6;
    }
    unsigned long long word = __ballot(c);
    if (lane == 0) {
      denseG[(size_t)i * 48 + w] = word;
      if (w == rc) diagG[i] = word;
      else if (word) {
        unsigned long long tt = word;
        while (tt) {
          int b = __builtin_ctzll(tt); tt &= tt - 1;
          int slot = atomicAdd(&cntGi[i], 1);
          if (slot < FCAP) entG[i * FCAP + slot] = (unsigned short)(w * 64 + b);
        }
      }
    }
  }
}

// ---------------- K5: sparse serial greedy scan + final outputs (fused) ----------------
__global__ __launch_bounds__(256) void k_final(
    const unsigned long long* __restrict__ denseG, const unsigned long long* __restrict__ diagG,
    const unsigned short* __restrict__ entG, const int* __restrict__ cntGi,
    const int* __restrict__ svalid, const int* __restrict__ sortIdx,
    const double* __restrict__ sel_s, const int* __restrict__ sel_lab,
    const double* __restrict__ sel_box, float* __restrict__ out) {
  __shared__ unsigned long long diagL[NROWS_PAD];
  __shared__ unsigned short entL[NROWS_PAD * FCAP];
  __shared__ unsigned short cntL[NROWS_PAD];
  __shared__ unsigned long long validL[48];
  __shared__ unsigned long long hasWL[48];
  __shared__ unsigned long long keepWL[48];
  __shared__ unsigned char keepO[NROWS_PAD];
  const int t = threadIdx.x;
  const int lane = t & 63;

  for (int k = t; k < NSEL; k += 256) diagL[k] = diagG[k];
  for (int k = NSEL + t; k < NROWS_PAD; k += 256) diagL[k] = 0ull;
  uint2* e2 = (uint2*)entL; const uint2* eg2 = (const uint2*)entG;   // 8B = one row's FCAP
  for (int k = t; k < NSEL; k += 256) e2[k] = eg2[k];
  for (int k = NSEL + t; k < NROWS_PAD; k += 256) { uint2 z; z.x = 0; z.y = 0; e2[k] = z; }
  for (int k = t; k < NSEL; k += 256) cntL[k] = (unsigned short)cntGi[k];
  for (int k = NSEL + t; k < NROWS_PAD; k += 256) cntL[k] = 0;
  for (int i0 = t; i0 < NROWS_PAD; i0 += 256) {
    bool f = (i0 < NSEL) && (svalid[i0] != 0);
    unsigned long long b = __ballot(f);
    if ((t & 63) == 0) validL[i0 >> 6] = b;
  }
  __syncthreads();

  if (t < 64) {                    // wave 0: serial greedy scan
    for (int w = 0; w < NWORDS; w++) {
      int i = w * 64 + lane;
      bool f = (diagL[i] != 0ull) || (cntL[i] != 0);
      unsigned long long b = __ballot(f);
      if (lane == 0) hasWL[w] = b;
    }
    unsigned long long rem = 0ull;    // lane j: removed bits in word j (cross-chunk)
    unsigned long long keep = 0ull;   // lane j: final keep word j
    for (int w = 0; w < NWORDS; w++) {
      unsigned long long vw = validL[w];
      unsigned long long remw = shfl64(rem, w);
      unsigned long long win = vw & ~remw;
      unsigned long long work = hasWL[w];
      while (work) {
        int d = __builtin_ctzll(work); work &= work - 1;
        if ((win >> d) & 1ull) {
          int i = w * 64 + d;
          win &= ~diagL[i];                       // intra-chunk suppression (bits > d only)
          int c = cntL[i];
          if (c > FCAP) {
            unsigned long long rowj = (lane < NWORDS) ? denseG[(size_t)i * 48 + lane] : 0ull;
            rem |= rowj;                          // garbage lanes < w already consumed
          } else {
            for (int k = 0; k < c; k++) {
              int j = entL[i * FCAP + k];
              if ((j >> 6) == lane) rem |= 1ull << (j & 63);
            }
          }
        }
      }
      if (lane == w) keep = win;
    }
    if (lane < NWORDS) keepWL[lane] = keep;
  }
  __syncthreads();

  // scatter keep bits to original indices, then write outputs
  for (int r = t; r < NSEL; r += 256)
    keepO[sortIdx[r]] = (unsigned char)((keepWL[r >> 6] >> (r & 63)) & 1ull);
  __syncthreads();
  for (int i = t; i < NSEL; i += 256) {
#pragma unroll
    for (int c = 0; c < 4; c++) {
      double v = sel_box[4 * i + c] / 1280.0;
      v = fmin(fmax(v, 0.0), 1.0);
      out[4 * i + c] = (float)v;
    }
    out[12000 + i] = (float)sel_s[i];
    out[15000 + i] = (float)sel_lab[i];
    out[18000 + i] = keepO[i] ? 1.0f : 0.0f;
  }
}

// ---------------- launch ----------------
extern "C" void kernel_launch(void* const* d_in, const int* in_sizes, int n_in,
                              void* d_out, int out_size, void* d_ws, size_t ws_size,
                              hipStream_t stream) {
  P21 P;
  for (int l = 0; l < 3; l++) {
    P.feat[l] = (const float*)d_in[7 * l + 0];
    P.Wobj[l] = (const float*)d_in[7 * l + 1];
    P.bobj[l] = (const float*)d_in[7 * l + 2];
    P.Wcls[l] = (const float*)d_in[7 * l + 3];
    P.bcls[l] = (const float*)d_in[7 * l + 4];
    P.Wreg[l] = (const float*)d_in[7 * l + 5];
    P.breg[l] = (const float*)d_in[7 * l + 6];
  }

  char* ws = (char*)d_ws;
  size_t off = 0;
  auto alloc = [&](size_t bytes) -> char* {
    char* p = ws + off;
    off += (bytes + 15) & ~(size_t)15;
    return p;
  };
  double* score_d  = (double*)alloc((size_t)NTOT * 8);
  double* box_d    = (double*)alloc((size_t)NTOT * 4 * 8);
  int*    label_d  = (int*)   alloc((size_t)NTOT * 4);
  double* obj_t    = (double*)alloc((size_t)NTOT * 8);
  double* reg_t    = (double*)alloc((size_t)NTOT * 4 * 8);
  double* cmax     = (double*)alloc((size_t)NSLC * NTOT * 8);
  int*    clab     = (int*)   alloc((size_t)NSLC * NTOT * 4);
  double* W64      = (double*)alloc((size_t)3 * WPER * 8);
  double* sel_s    = (double*)alloc((size_t)NSEL * 8);
  double* sel_box  = (double*)alloc((size_t)NSEL * 4 * 8);
  int*    sel_lab  = (int*)   alloc((size_t)NSEL * 4);
  int*    sortIdx  = (int*)   alloc((size_t)NSEL * 4);
  double* sbox     = (double*)alloc((size_t)NSEL * 4 * 8);
  int*    svalid   = (int*)   alloc((size_t)NSEL * 4);
  double* cand_s   = (double*)alloc((size_t)3 * CAND_CAP * 8);
  int*    cand_g   = (int*)   alloc((size_t)3 * CAND_CAP * 4);
  unsigned long long* denseG = (unsigned long long*)alloc((size_t)NSEL * 48 * 8);
  unsigned long long* diagG  = (unsigned long long*)alloc((size_t)NSEL * 8);
  unsigned short*     entG   = (unsigned short*)alloc((size_t)NSEL * FCAP * 2);
  unsigned* hist   = (unsigned*)alloc((size_t)3 * 65536 * 4);   // zero block: hist+cnt+cntGi
  unsigned* cnt    = (unsigned*)alloc(16);
  int*      cntGi  = (int*)   alloc((size_t)NSEL * 4);
  unsigned* cutB   = (unsigned*)alloc(16);

  k_setup   <<<(ZTOT + 255) / 256, 256, 0, stream>>>(P, hist, W64);
  dim3 cgrid(132, 11, 1);
  k_conv_chunk<<<cgrid, 256, 0, stream>>>(P, W64, obj_t, reg_t, cmax, clab);
  k_combine <<<NGRP, 64, 0, stream>>>(obj_t, reg_t, cmax, clab, score_d, label_d, box_d, hist);
  k_scan    <<<3, 256, 0, stream>>>(hist, cutB);
  k_compact <<<NGRP, 64, 0, stream>>>(score_d, cutB, cnt, cand_s, cand_g);
  dim3 rgrid(CAND_CAP / 4, 3, 1);
  k_rank    <<<rgrid, 256, 0, stream>>>(cand_s, cand_g, cnt, label_d, box_d,
                                        sel_s, sel_lab, sel_box);
  k_order   <<<NSEL, 256, 0, stream>>>(sel_s, sel_lab, sel_box, sortIdx, sbox, svalid);
  k_mask    <<<NTRI, 256, 0, stream>>>(sbox, denseG, diagG, entG, cntGi);
  k_final   <<<1, 256, 0, stream>>>(denseG, diagG, entG, cntGi, svalid, sortIdx,
                                    sel_s, sel_lab, sel_box, (float*)d_out);
}